// Round 7
// baseline (2757.122 us; speedup 1.0000x reference)
//
#include <hip/hip_runtime.h>
#include <hip/hip_bf16.h>

typedef unsigned short u16;
typedef __bf16 bf16x8 __attribute__((ext_vector_type(8)));
typedef short  short8 __attribute__((ext_vector_type(8)));
typedef float  f32x4  __attribute__((ext_vector_type(4)));
typedef u16    u16x4  __attribute__((ext_vector_type(4)));

#define BB 2
#define SS 2048
#define DD 2048
#define HH 16
#define HDIM 128
#define MM (BB * SS)   // 4096 tokens
// 1/sqrt(128) * log2(e), folded into wq/bq at conversion
#define KSCALE 0.12752039505554602f

// ---- DIAGNOSTIC amplification factors (idempotent reps; true time = dur/REP) ----
#define REP_CONV 16
#define REP_QKV  5
#define REP_ATTN 6
#define REP_OUT  10

static __device__ __forceinline__ f32x4 mfma16(short8 a, short8 b, f32x4 c) {
    return __builtin_amdgcn_mfma_f32_16x16x32_bf16(
        __builtin_bit_cast(bf16x8, a), __builtin_bit_cast(bf16x8, b), c, 0, 0, 0);
}

static __device__ __forceinline__ u16 f2bf(float f) {
    union { float f; unsigned u; } v; v.f = f;
    unsigned r = v.u + 0x7fffu + ((v.u >> 16) & 1u);
    return (u16)(r >> 16);
}

static __device__ __forceinline__ uint4 pack8(float4 a, float4 b) {
    uint4 o;
    o.x = (unsigned)f2bf(a.x) | ((unsigned)f2bf(a.y) << 16);
    o.y = (unsigned)f2bf(a.z) | ((unsigned)f2bf(a.w) << 16);
    o.z = (unsigned)f2bf(b.x) | ((unsigned)f2bf(b.y) << 16);
    o.w = (unsigned)f2bf(b.z) | ((unsigned)f2bf(b.w) << 16);
    return o;
}

static __device__ __forceinline__ void gload_lds16(const u16* g, u16* l) {
    __builtin_amdgcn_global_load_lds(
        (const __attribute__((address_space(1))) unsigned int*)g,
        (__attribute__((address_space(3))) unsigned int*)l, 16, 0, 0);
}

// All 7 fp32->bf16 conversions fused. wq segment is pre-scaled by KSCALE.
__global__ __launch_bounds__(256) void conv_all(
    const float* __restrict__ q, const float* __restrict__ k, const float* __restrict__ v,
    const float* __restrict__ wq, const float* __restrict__ wk,
    const float* __restrict__ wv, const float* __restrict__ wo,
    u16* __restrict__ out)
{
    constexpr int n1 = MM * DD / 8;
    constexpr int nw = DD * DD / 8;
    constexpr int total = 3 * n1 + 4 * nw;
    const int stride = gridDim.x * blockDim.x;
    for (int rep = 0; rep < REP_CONV; ++rep) {
        for (int i = blockIdx.x * blockDim.x + threadIdx.x; i < total; i += stride) {
            const float* s; int j = i; float sc = 1.f;
            if (j < n1)            { s = q; }
            else if (j < 2 * n1)   { s = k;  j -= n1; }
            else if (j < 3 * n1)   { s = v;  j -= 2 * n1; }
            else {
                j -= 3 * n1;
                if (j < nw)        { s = wq; sc = KSCALE; }
                else if (j < 2*nw) { s = wk; j -= nw; }
                else if (j < 3*nw) { s = wv; j -= 2 * nw; }
                else               { s = wo; j -= 3 * nw; }
            }
            const float4* sp = (const float4*)s + (size_t)j * 2;
            float4 a = sp[0], bb2 = sp[1];
            a.x *= sc; a.y *= sc; a.z *= sc; a.w *= sc;
            bb2.x *= sc; bb2.y *= sc; bb2.z *= sc; bb2.w *= sc;
            ((uint4*)out)[i] = pack8(a, bb2);
        }
    }
}

// Q/K/V projections in ONE launch: grid.z = 0/1/2 selects tensor.
__global__ __launch_bounds__(256, 3) void gemm_qkv(
    const u16* __restrict__ A0, const u16* __restrict__ W0,
    const float* __restrict__ bq, const float* __restrict__ bk,
    const float* __restrict__ bv, u16* __restrict__ C0)
{
    __shared__ u16 S[128 * 132];            // staging (8K elems) U transposed-C bounce
    u16* Al = S;
    u16* Bl = S + 4096;

    const int z = blockIdx.z;
    const u16* A  = A0 + (size_t)z * MM * DD;
    const u16* Wb = W0 + (size_t)z * DD * DD;
    const float* bias = (z == 0) ? bq : (z == 1 ? bk : bv);
    const float bsc = (z == 0) ? KSCALE : 1.f;

    const int tid = threadIdx.x;
    const int lane = tid & 63;
    const int lg = lane >> 4, li = lane & 15;
    const int wid = tid >> 6;
    const int brow = blockIdx.x * 128, bcol = blockIdx.y * 128;
    const int wm = wid >> 1, wn = wid & 1;

    const int srow = tid >> 2;
    const int scol = (tid & 3) * 8;

    const u16* aptr = A  + (size_t)(brow + srow) * DD + scol;
    const u16* bptr = Wb + (size_t)(bcol + srow) * DD + scol;
    const size_t half = (size_t)64 * DD;
    const f32x4 zero = {0.f, 0.f, 0.f, 0.f};

    for (int rep = 0; rep < REP_QKV; ++rep) {
        f32x4 acc[4][4];
#pragma unroll
        for (int i = 0; i < 4; ++i)
#pragma unroll
            for (int j = 0; j < 4; ++j) acc[i][j] = zero;

        for (int kt = 0; kt < DD; kt += 32) {
            gload_lds16(aptr + kt,        &Al[tid * 8]);
            gload_lds16(aptr + half + kt, &Al[2048 + tid * 8]);
            gload_lds16(bptr + kt,        &Bl[tid * 8]);
            gload_lds16(bptr + half + kt, &Bl[2048 + tid * 8]);
            __syncthreads();

            short8 af[4], bf[4];
#pragma unroll
            for (int mi = 0; mi < 4; ++mi)
                af[mi] = *(const short8*)(&Al[(wm * 64 + mi * 16 + li) * 32 + lg * 8]);
#pragma unroll
            for (int ni = 0; ni < 4; ++ni)
                bf[ni] = *(const short8*)(&Bl[(wn * 64 + ni * 16 + li) * 32 + lg * 8]);
#pragma unroll
            for (int mi = 0; mi < 4; ++mi)
#pragma unroll
                for (int ni = 0; ni < 4; ++ni)
                    acc[mi][ni] = mfma16(af[mi], bf[ni], acc[mi][ni]);
            __syncthreads();
        }

        if (z == 2) {
            // transposed epilogue: bounce through LDS (reuse S), write [D][M]
            u16* Cl = S;
#pragma unroll
            for (int ni = 0; ni < 4; ++ni) {
                const int cc = wn * 64 + ni * 16 + li;
                const float bvv = bias[bcol + cc];
#pragma unroll
                for (int mi = 0; mi < 4; ++mi)
#pragma unroll
                    for (int r = 0; r < 4; ++r) {
                        const int rr = wm * 64 + mi * 16 + lg * 4 + r;
                        Cl[cc * 132 + rr] = f2bf(acc[mi][ni][r] + bvv);
                    }
            }
            __syncthreads();
            const int row = tid >> 1;
            const int hcol = (tid & 1) * 64;
            u16* dst = C0 + (size_t)2 * MM * DD + (size_t)(bcol + row) * MM + brow + hcol;
#pragma unroll
            for (int c = 0; c < 8; ++c)
                *(short8*)(dst + c * 8) = *(const short8*)(&Cl[row * 132 + hcol + c * 8]);
        } else {
            u16* Cp = C0 + (size_t)z * MM * DD;
#pragma unroll
            for (int ni = 0; ni < 4; ++ni) {
                const int col = bcol + wn * 64 + ni * 16 + li;
                const float bvv = bias[col] * bsc;
#pragma unroll
                for (int mi = 0; mi < 4; ++mi)
#pragma unroll
                    for (int r = 0; r < 4; ++r) {
                        const int row = brow + wm * 64 + mi * 16 + lg * 4 + r;
                        Cp[(size_t)row * DD + col] = f2bf(acc[mi][ni][r] + bvv);
                    }
            }
        }
        __syncthreads();   // protect LDS reuse across reps
    }
}

// O-projection: C fp32 = A(bf16) @ W^T + bias (m97 structure)
__global__ __launch_bounds__(256) void gemm_out(
    const u16* __restrict__ A, const u16* __restrict__ Wb,
    const float* __restrict__ bias, float* __restrict__ Cp)
{
    __shared__ u16 Al[128 * 32];
    __shared__ u16 Bl[128 * 32];

    const int tid = threadIdx.x;
    const int lane = tid & 63;
    const int lg = lane >> 4, li = lane & 15;
    const int wid = tid >> 6;
    const int brow = blockIdx.x * 128, bcol = blockIdx.y * 128;
    const int wm = wid >> 1, wn = wid & 1;

    const int srow = tid >> 2;
    const int scol = (tid & 3) * 8;

    const u16* aptr = A  + (size_t)(brow + srow) * DD + scol;
    const u16* bptr = Wb + (size_t)(bcol + srow) * DD + scol;
    const size_t half = (size_t)64 * DD;
    const f32x4 zero = {0.f, 0.f, 0.f, 0.f};

    for (int rep = 0; rep < REP_OUT; ++rep) {
        f32x4 acc[4][4];
#pragma unroll
        for (int i = 0; i < 4; ++i)
#pragma unroll
            for (int j = 0; j < 4; ++j) acc[i][j] = zero;

        for (int kt = 0; kt < DD; kt += 32) {
            gload_lds16(aptr + kt,        &Al[tid * 8]);
            gload_lds16(aptr + half + kt, &Al[2048 + tid * 8]);
            gload_lds16(bptr + kt,        &Bl[tid * 8]);
            gload_lds16(bptr + half + kt, &Bl[2048 + tid * 8]);
            __syncthreads();

            short8 af[4], bf[4];
#pragma unroll
            for (int mi = 0; mi < 4; ++mi)
                af[mi] = *(const short8*)(&Al[(wm * 64 + mi * 16 + li) * 32 + lg * 8]);
#pragma unroll
            for (int ni = 0; ni < 4; ++ni)
                bf[ni] = *(const short8*)(&Bl[(wn * 64 + ni * 16 + li) * 32 + lg * 8]);
#pragma unroll
            for (int mi = 0; mi < 4; ++mi)
#pragma unroll
                for (int ni = 0; ni < 4; ++ni)
                    acc[mi][ni] = mfma16(af[mi], bf[ni], acc[mi][ni]);
            __syncthreads();
        }

#pragma unroll
        for (int ni = 0; ni < 4; ++ni) {
            const int col = bcol + wn * 64 + ni * 16 + li;
            const float bvv = bias[col];
#pragma unroll
            for (int mi = 0; mi < 4; ++mi)
#pragma unroll
                for (int r = 0; r < 4; ++r) {
                    const int row = brow + wm * 64 + mi * 16 + lg * 4 + r;
                    Cp[(size_t)row * DD + col] = acc[mi][ni][r] + bvv;
                }
        }
        __syncthreads();
    }
}

// Flash attention, causal, swapped-QK^T, QBLK=128 (4 waves x 32 q each).
__global__ __launch_bounds__(256) void flash_attn(
    const u16* __restrict__ Q, const u16* __restrict__ Kp,
    const u16* __restrict__ Vt, u16* __restrict__ O)
{
    constexpr int SP = 72;
    __shared__ u16 lds[16384 + 4 * 32 * SP];
    u16* Kl = lds;             // K tile [64 kv][128 d], swizzled
    u16* Vl = lds + 8192;      // V^T tile [128 d][64 kv], swizzled
    u16* Pl = lds + 16384;     // per-wave P [32 q][64 kv]

    const int tid = threadIdx.x;
    const int wid = tid >> 6, lane = tid & 63;
    const int lg = lane >> 4, li = lane & 15;
    const int qt = (int)gridDim.x - 1 - (int)blockIdx.x;  // heavy tiles first
    const int h = blockIdx.y, b = blockIdx.z;
    const int nt = 2 * qt + 2;
    const int qbase = qt * 128 + wid * 32;                // wave's q origin

    // staging address precompute
    const int rK0 = tid >> 4, wK0 = tid & 15;
    const int bK0 = ((wK0 * 16) ^ ((rK0 & 7) << 4)) >> 1;
    const int rV0 = tid >> 3, wV0 = tid & 7;
    const int bV0 = ((wV0 * 16) ^ ((rV0 & 7) << 4)) >> 1;
    const u16* kbase = Kp + (size_t)(b * SS + rK0) * DD + h * HDIM + bK0;
    const u16* vbase = Vt + (size_t)(h * HDIM + rV0) * MM + b * SS + bV0;

    // Q fragments: 2 q-halves (B-frag col = q = qh*16+li)
    short8 qf[4][2];
    {
        const u16* qp0 = Q + (size_t)(b * SS + qbase + li) * DD + h * HDIM + lg * 8;
#pragma unroll
        for (int qh = 0; qh < 2; ++qh)
#pragma unroll
            for (int s = 0; s < 4; ++s)
                qf[s][qh] = *(const short8*)(qp0 + (size_t)qh * 16 * DD + s * 32);
    }

    const f32x4 zero = {0.f, 0.f, 0.f, 0.f};

    for (int rep = 0; rep < REP_ATTN; ++rep) {
        float m_r[2], l_r[2];
        m_r[0] = m_r[1] = -__builtin_inff();
        l_r[0] = l_r[1] = 0.f;
        f32x4 accO[8][2];          // O^T: row d = mb*16+lg*4+r, col q = qh*16+li
#pragma unroll
        for (int d = 0; d < 8; ++d) accO[d][0] = accO[d][1] = zero;

        for (int j = 0; j < nt; ++j) {
            // ---- stage K and V^T (single buffer) ----
#pragma unroll
            for (int i_ = 0; i_ < 4; ++i_) {
                gload_lds16(kbase + (size_t)(j * 64 + i_ * 16) * DD, &Kl[(i_ * 256 + tid) * 8]);
                gload_lds16(vbase + (size_t)(i_ * 32) * MM + j * 64, &Vl[(i_ * 256 + tid) * 8]);
            }
            __syncthreads();

            // wave-uniform: skip fully-masked diagonal tiles
            if (j * 64 <= qbase + 31) {
                // ---- scores TRANSPOSED: S^T[64 kv][32 q], A=K, B=Q ----
                f32x4 accS[4][2];
#pragma unroll
                for (int nb = 0; nb < 4; ++nb) accS[nb][0] = accS[nb][1] = zero;
                __builtin_amdgcn_s_setprio(1);
#pragma unroll
                for (int s = 0; s < 4; ++s) {
#pragma unroll
                    for (int nb = 0; nb < 4; ++nb) {
                        const int R = nb * 16 + li;
                        const int e = ((s * 64 + lg * 16) ^ ((R & 7) << 4)) >> 1;
                        short8 kf = *(const short8*)(&Kl[R * 128 + e]);
#pragma unroll
                        for (int qh = 0; qh < 2; ++qh)
                            accS[nb][qh] = mfma16(kf, qf[s][qh], accS[nb][qh]);
                    }
                }
                __builtin_amdgcn_s_setprio(0);

                // ---- online softmax, per-lane (2 q's), exp2 domain ----
                const bool domask = (j * 64 + 63 > qbase);
                float rmax[2];
                rmax[0] = rmax[1] = -__builtin_inff();
#pragma unroll
                for (int nb = 0; nb < 4; ++nb)
#pragma unroll
                    for (int qh = 0; qh < 2; ++qh)
#pragma unroll
                        for (int r = 0; r < 4; ++r) {
                            float t = accS[nb][qh][r];
                            if (domask && (j * 64 + nb * 16 + lg * 4 + r >
                                           qbase + qh * 16 + li)) t = -__builtin_inff();
                            accS[nb][qh][r] = t;
                            rmax[qh] = fmaxf(rmax[qh], t);
                        }
#pragma unroll
                for (int qh = 0; qh < 2; ++qh) {
                    rmax[qh] = fmaxf(rmax[qh], __shfl_xor(rmax[qh], 16, 64));
                    rmax[qh] = fmaxf(rmax[qh], __shfl_xor(rmax[qh], 32, 64));
                }

                // defer-max (T13)
                const bool need = (rmax[0] - m_r[0] > 11.5f) || (rmax[1] - m_r[1] > 11.5f);
                if (__any(need)) {
#pragma unroll
                    for (int qh = 0; qh < 2; ++qh) {
                        const float mn = fmaxf(m_r[qh], rmax[qh]);
                        const float sf = exp2f(m_r[qh] - mn);
                        m_r[qh] = mn;
                        l_r[qh] *= sf;
#pragma unroll
                        for (int mb = 0; mb < 8; ++mb)
#pragma unroll
                            for (int r = 0; r < 4; ++r) accO[mb][qh][r] *= sf;
                    }
                }

                float ls[2] = {0.f, 0.f};
#pragma unroll
                for (int nb = 0; nb < 4; ++nb)
#pragma unroll
                    for (int qh = 0; qh < 2; ++qh)
#pragma unroll
                        for (int r = 0; r < 4; ++r) {
                            const float e = exp2f(accS[nb][qh][r] - m_r[qh]);
                            accS[nb][qh][r] = e;
                            ls[qh] += e;
                        }
#pragma unroll
                for (int qh = 0; qh < 2; ++qh) {
                    ls[qh] += __shfl_xor(ls[qh], 16, 64);
                    ls[qh] += __shfl_xor(ls[qh], 32, 64);
                    l_r[qh] += ls[qh];
                }

                // ---- P -> LDS, packed b64 writes ----
#pragma unroll
                for (int nb = 0; nb < 4; ++nb)
#pragma unroll
                    for (int qh = 0; qh < 2; ++qh) {
                        u16x4 pk;
                        pk.x = f2bf(accS[nb][qh][0]);
                        pk.y = f2bf(accS[nb][qh][1]);
                        pk.z = f2bf(accS[nb][qh][2]);
                        pk.w = f2bf(accS[nb][qh][3]);
                        *(u16x4*)(&Pl[(wid * 32 + qh * 16 + li) * SP + nb * 16 + lg * 4]) = pk;
                    }

                // ---- PV transposed: O^T += V^T @ P^T ----
                __builtin_amdgcn_s_setprio(1);
#pragma unroll
                for (int s2 = 0; s2 < 2; ++s2) {
                    short8 pf[2];
#pragma unroll
                    for (int qh = 0; qh < 2; ++qh)
                        pf[qh] = *(const short8*)(&Pl[(wid * 32 + qh * 16 + li) * SP +
                                                      s2 * 32 + lg * 8]);
#pragma unroll
                    for (int mb = 0; mb < 8; ++mb) {
                        const int R2 = mb * 16 + li;
                        const int e2 = ((s2 * 64 + lg * 16) ^ ((R2 & 7) << 4)) >> 1;
                        short8 vf = *(const short8*)(&Vl[R2 * 64 + e2]);
#pragma unroll
                        for (int qh = 0; qh < 2; ++qh)
                            accO[mb][qh] = mfma16(vf, pf[qh], accO[mb][qh]);
                    }
                }
                __builtin_amdgcn_s_setprio(0);
            }
            __syncthreads();
        }

        // ---- epilogue: un-transpose via per-wave LDS bounce ----
        {
            float linv[2] = {1.f / l_r[0], 1.f / l_r[1]};
            u16* Wl = lds + wid * 4096;               // 32 q x 128 d per wave
#pragma unroll
            for (int mb = 0; mb < 8; ++mb)
#pragma unroll
                for (int qh = 0; qh < 2; ++qh) {
                    const int q_l = qh * 16 + li;
                    const int dbase = mb * 16 + lg * 4;
                    u16x4 pk;
                    pk.x = f2bf(accO[mb][qh][0] * linv[qh]);
                    pk.y = f2bf(accO[mb][qh][1] * linv[qh]);
                    pk.z = f2bf(accO[mb][qh][2] * linv[qh]);
                    pk.w = f2bf(accO[mb][qh][3] * linv[qh]);
                    *(u16x4*)(&Wl[q_l * 128 + (dbase ^ ((q_l & 7) << 4))]) = pk;
                }
            const int q_l = lane >> 1;
            const int d0 = (lane & 1) * 64;
            u16* op = O + (size_t)(b * SS + qt * 128 + wid * 32 + q_l) * DD + h * HDIM + d0;
#pragma unroll
            for (int c = 0; c < 8; ++c) {
                short8 vv = *(const short8*)(&Wl[q_l * 128 + ((d0 + c * 8) ^ ((q_l & 7) << 4))]);
                *(short8*)(op + c * 8) = vv;
            }
        }
        __syncthreads();   // protect LDS reuse across reps
    }
}

extern "C" void kernel_launch(void* const* d_in, const int* in_sizes, int n_in,
                              void* d_out, int out_size, void* d_ws, size_t ws_size,
                              hipStream_t stream)
{
    const float* queries = (const float*)d_in[0];
    const float* keys    = (const float*)d_in[1];
    const float* values  = (const float*)d_in[2];
    // d_in[3] = attention_mask: causal by construction
    const float* wq = (const float*)d_in[4];
    const float* bq = (const float*)d_in[5];
    const float* wk = (const float*)d_in[6];
    const float* bk = (const float*)d_in[7];
    const float* wv = (const float*)d_in[8];
    const float* bv = (const float*)d_in[9];
    const float* wo = (const float*)d_in[10];
    const float* bo = (const float*)d_in[11];

    const int NMD = MM * DD;
    const int NWW = DD * DD;

    u16* qb  = (u16*)d_ws;                      // converted inputs (bf16), contiguous
    u16* wqb = qb  + (size_t)3 * NMD;           // converted weights (wq pre-scaled)
    u16* wob = wqb + (size_t)3 * NWW;
    u16* qw  = wob + (size_t)NWW;               // q proj [M][D] (KSCALE folded)
                                                // kw = qw + NMD   [M][D]
                                                // vtw = qw + 2*NMD TRANSPOSED [D][M]
    u16* aw  = qw  + (size_t)3 * NMD;           // attention output [M][D]
    (void)in_sizes; (void)n_in; (void)out_size; (void)ws_size;

    dim3 blk(256);
    dim3 gridC(2048);
    dim3 gridQKV(MM / 128, DD / 128, 3);        // (32, 16, 3) = 1536 blocks
    dim3 gridO(MM / 128, DD / 128);             // (32, 16)
    dim3 gridA(SS / 128, HH, BB);               // (16, 16, 2)

    conv_all<<<gridC, blk, 0, stream>>>(queries, keys, values, wq, wk, wv, wo, qb);
    gemm_qkv<<<gridQKV, blk, 0, stream>>>(qb, wqb, bq, bk, bv, qw);
    flash_attn<<<gridA, blk, 0, stream>>>(qw, qw + (size_t)NMD, qw + (size_t)2 * NMD, aw);
    gemm_out<<<gridO, blk, 0, stream>>>(aw, wob, bo, (float*)d_out);
}

// Round 8
// 349.129 us; speedup vs baseline: 7.8971x; 7.8971x over previous
//
#include <hip/hip_runtime.h>
#include <hip/hip_bf16.h>

typedef unsigned short u16;
typedef __bf16 bf16x8 __attribute__((ext_vector_type(8)));
typedef short  short8 __attribute__((ext_vector_type(8)));
typedef float  f32x4  __attribute__((ext_vector_type(4)));
typedef u16    u16x4  __attribute__((ext_vector_type(4)));

#define BB 2
#define SS 2048
#define DD 2048
#define HH 16
#define HDIM 128
#define MM (BB * SS)   // 4096 tokens
// 1/sqrt(128) * log2(e), folded into wq/bq at conversion
#define KSCALE 0.12752039505554602f

static __device__ __forceinline__ f32x4 mfma16(short8 a, short8 b, f32x4 c) {
    return __builtin_amdgcn_mfma_f32_16x16x32_bf16(
        __builtin_bit_cast(bf16x8, a), __builtin_bit_cast(bf16x8, b), c, 0, 0, 0);
}

static __device__ __forceinline__ u16 f2bf(float f) {
    union { float f; unsigned u; } v; v.f = f;
    unsigned r = v.u + 0x7fffu + ((v.u >> 16) & 1u);
    return (u16)(r >> 16);
}

static __device__ __forceinline__ float bf2f(u16 v) {
    union { unsigned u; float f; } t; t.u = ((unsigned)v) << 16;
    return t.f;
}

static __device__ __forceinline__ uint4 pack8(float4 a, float4 b) {
    uint4 o;
    o.x = (unsigned)f2bf(a.x) | ((unsigned)f2bf(a.y) << 16);
    o.y = (unsigned)f2bf(a.z) | ((unsigned)f2bf(a.w) << 16);
    o.z = (unsigned)f2bf(b.x) | ((unsigned)f2bf(b.y) << 16);
    o.w = (unsigned)f2bf(b.z) | ((unsigned)f2bf(b.w) << 16);
    return o;
}

static __device__ __forceinline__ void gload_lds16(const u16* g, u16* l) {
    __builtin_amdgcn_global_load_lds(
        (const __attribute__((address_space(1))) unsigned int*)g,
        (__attribute__((address_space(3))) unsigned int*)l, 16, 0, 0);
}

// All 7 fp32->bf16 conversions fused. wq segment is pre-scaled by KSCALE.
__global__ __launch_bounds__(256) void conv_all(
    const float* __restrict__ q, const float* __restrict__ k, const float* __restrict__ v,
    const float* __restrict__ wq, const float* __restrict__ wk,
    const float* __restrict__ wv, const float* __restrict__ wo,
    u16* __restrict__ out)
{
    constexpr int n1 = MM * DD / 8;
    constexpr int nw = DD * DD / 8;
    constexpr int total = 3 * n1 + 4 * nw;
    const int stride = gridDim.x * blockDim.x;
    for (int i = blockIdx.x * blockDim.x + threadIdx.x; i < total; i += stride) {
        const float* s; int j = i; float sc = 1.f;
        if (j < n1)            { s = q; }
        else if (j < 2 * n1)   { s = k;  j -= n1; }
        else if (j < 3 * n1)   { s = v;  j -= 2 * n1; }
        else {
            j -= 3 * n1;
            if (j < nw)        { s = wq; sc = KSCALE; }
            else if (j < 2*nw) { s = wk; j -= nw; }
            else if (j < 3*nw) { s = wv; j -= 2 * nw; }
            else               { s = wo; j -= 3 * nw; }
        }
        const float4* sp = (const float4*)s + (size_t)j * 2;
        float4 a = sp[0], bb2 = sp[1];
        a.x *= sc; a.y *= sc; a.z *= sc; a.w *= sc;
        bb2.x *= sc; bb2.y *= sc; bb2.z *= sc; bb2.w *= sc;
        ((uint4*)out)[i] = pack8(a, bb2);
    }
}

// Q/K/V projections in ONE launch: grid.z = 0/1/2 selects tensor.
__global__ __launch_bounds__(256, 3) void gemm_qkv(
    const u16* __restrict__ A0, const u16* __restrict__ W0,
    const float* __restrict__ bq, const float* __restrict__ bk,
    const float* __restrict__ bv, u16* __restrict__ C0)
{
    __shared__ u16 S[128 * 132];            // staging (8K elems) U transposed-C bounce
    u16* Al = S;
    u16* Bl = S + 4096;

    const int z = blockIdx.z;
    const u16* A  = A0 + (size_t)z * MM * DD;
    const u16* Wb = W0 + (size_t)z * DD * DD;
    const float* bias = (z == 0) ? bq : (z == 1 ? bk : bv);
    const float bsc = (z == 0) ? KSCALE : 1.f;

    const int tid = threadIdx.x;
    const int lane = tid & 63;
    const int lg = lane >> 4, li = lane & 15;
    const int wid = tid >> 6;
    const int brow = blockIdx.x * 128, bcol = blockIdx.y * 128;
    const int wm = wid >> 1, wn = wid & 1;

    const int srow = tid >> 2;
    const int scol = (tid & 3) * 8;

    const f32x4 zero = {0.f, 0.f, 0.f, 0.f};
    f32x4 acc[4][4];
#pragma unroll
    for (int i = 0; i < 4; ++i)
#pragma unroll
        for (int j = 0; j < 4; ++j) acc[i][j] = zero;

    const u16* aptr = A  + (size_t)(brow + srow) * DD + scol;
    const u16* bptr = Wb + (size_t)(bcol + srow) * DD + scol;
    const size_t half = (size_t)64 * DD;

    for (int kt = 0; kt < DD; kt += 32) {
        gload_lds16(aptr + kt,        &Al[tid * 8]);
        gload_lds16(aptr + half + kt, &Al[2048 + tid * 8]);
        gload_lds16(bptr + kt,        &Bl[tid * 8]);
        gload_lds16(bptr + half + kt, &Bl[2048 + tid * 8]);
        __syncthreads();

        short8 af[4], bf[4];
#pragma unroll
        for (int mi = 0; mi < 4; ++mi)
            af[mi] = *(const short8*)(&Al[(wm * 64 + mi * 16 + li) * 32 + lg * 8]);
#pragma unroll
        for (int ni = 0; ni < 4; ++ni)
            bf[ni] = *(const short8*)(&Bl[(wn * 64 + ni * 16 + li) * 32 + lg * 8]);
#pragma unroll
        for (int mi = 0; mi < 4; ++mi)
#pragma unroll
            for (int ni = 0; ni < 4; ++ni)
                acc[mi][ni] = mfma16(af[mi], bf[ni], acc[mi][ni]);
        __syncthreads();
    }

    if (z == 2) {
        // transposed epilogue: bounce through LDS (reuse S), write [D][M]
        u16* Cl = S;
#pragma unroll
        for (int ni = 0; ni < 4; ++ni) {
            const int cc = wn * 64 + ni * 16 + li;
            const float bvv = bias[bcol + cc];
#pragma unroll
            for (int mi = 0; mi < 4; ++mi)
#pragma unroll
                for (int r = 0; r < 4; ++r) {
                    const int rr = wm * 64 + mi * 16 + lg * 4 + r;
                    Cl[cc * 132 + rr] = f2bf(acc[mi][ni][r] + bvv);
                }
        }
        __syncthreads();
        const int row = tid >> 1;
        const int hcol = (tid & 1) * 64;
        u16* dst = C0 + (size_t)2 * MM * DD + (size_t)(bcol + row) * MM + brow + hcol;
#pragma unroll
        for (int c = 0; c < 8; ++c)
            *(short8*)(dst + c * 8) = *(const short8*)(&Cl[row * 132 + hcol + c * 8]);
    } else {
        u16* Cp = C0 + (size_t)z * MM * DD;
#pragma unroll
        for (int ni = 0; ni < 4; ++ni) {
            const int col = bcol + wn * 64 + ni * 16 + li;
            const float bvv = bias[col] * bsc;
#pragma unroll
            for (int mi = 0; mi < 4; ++mi)
#pragma unroll
                for (int r = 0; r < 4; ++r) {
                    const int row = brow + wm * 64 + mi * 16 + lg * 4 + r;
                    Cp[(size_t)row * DD + col] = f2bf(acc[mi][ni][r] + bvv);
                }
        }
    }
}

// O-projection: C fp32 = A(bf16) @ W^T + bias (m97 structure)
__global__ __launch_bounds__(256) void gemm_out(
    const u16* __restrict__ A, const u16* __restrict__ Wb,
    const float* __restrict__ bias, float* __restrict__ Cp)
{
    __shared__ u16 Al[128 * 32];
    __shared__ u16 Bl[128 * 32];

    const int tid = threadIdx.x;
    const int lane = tid & 63;
    const int lg = lane >> 4, li = lane & 15;
    const int wid = tid >> 6;
    const int brow = blockIdx.x * 128, bcol = blockIdx.y * 128;
    const int wm = wid >> 1, wn = wid & 1;

    const int srow = tid >> 2;
    const int scol = (tid & 3) * 8;

    const f32x4 zero = {0.f, 0.f, 0.f, 0.f};
    f32x4 acc[4][4];
#pragma unroll
    for (int i = 0; i < 4; ++i)
#pragma unroll
        for (int j = 0; j < 4; ++j) acc[i][j] = zero;

    const u16* aptr = A  + (size_t)(brow + srow) * DD + scol;
    const u16* bptr = Wb + (size_t)(bcol + srow) * DD + scol;
    const size_t half = (size_t)64 * DD;

    for (int kt = 0; kt < DD; kt += 32) {
        gload_lds16(aptr + kt,        &Al[tid * 8]);
        gload_lds16(aptr + half + kt, &Al[2048 + tid * 8]);
        gload_lds16(bptr + kt,        &Bl[tid * 8]);
        gload_lds16(bptr + half + kt, &Bl[2048 + tid * 8]);
        __syncthreads();

        short8 af[4], bf[4];
#pragma unroll
        for (int mi = 0; mi < 4; ++mi)
            af[mi] = *(const short8*)(&Al[(wm * 64 + mi * 16 + li) * 32 + lg * 8]);
#pragma unroll
        for (int ni = 0; ni < 4; ++ni)
            bf[ni] = *(const short8*)(&Bl[(wn * 64 + ni * 16 + li) * 32 + lg * 8]);
#pragma unroll
        for (int mi = 0; mi < 4; ++mi)
#pragma unroll
            for (int ni = 0; ni < 4; ++ni)
                acc[mi][ni] = mfma16(af[mi], bf[ni], acc[mi][ni]);
        __syncthreads();
    }

#pragma unroll
    for (int ni = 0; ni < 4; ++ni) {
        const int col = bcol + wn * 64 + ni * 16 + li;
        const float bvv = bias[col];
#pragma unroll
        for (int mi = 0; mi < 4; ++mi)
#pragma unroll
            for (int r = 0; r < 4; ++r) {
                const int row = brow + wm * 64 + mi * 16 + lg * 4 + r;
                Cp[(size_t)row * DD + col] = acc[mi][ni][r] + bvv;
            }
    }
}

// Flash attention, causal, swapped-QK^T, QBLK=128, KV-CHUNKED (flash-decoding).
// Each block: one q-tile x one chunk of <=8 kv-tiles. 40 (qt,ch) pairs per (b,h):
//   qt 0..3: 1 chunk (direct write); qt 4..7: 2; qt 8..11: 3; qt 12..15: 4.
// Multi-chunk blocks write unnormalized partial O^T (bf16 [d][q]) + m,l (f32).
__global__ __launch_bounds__(256) void flash_attn(
    const u16* __restrict__ Q, const u16* __restrict__ Kp,
    const u16* __restrict__ Vt, u16* __restrict__ O,
    u16* __restrict__ PartO, float* __restrict__ PartML)
{
    constexpr int SP = 72;
    __shared__ u16 lds[16384 + 4 * 32 * SP];
    u16* Kl = lds;             // K tile [64 kv][128 d], swizzled
    u16* Vl = lds + 8192;      // V^T tile [128 d][64 kv], swizzled
    u16* Pl = lds + 16384;     // per-wave P [32 q][64 kv]

    const int tid = threadIdx.x;
    const int wid = tid >> 6, lane = tid & 63;
    const int lg = lane >> 4, li = lane & 15;
    const int h = blockIdx.y, b = blockIdx.z;

    // flat (qt, chunk) decode; heavy chunks first
    const int f = 39 - (int)blockIdx.x;
    int qt, ch;
    if (f < 4)       { qt = f;               ch = 0; }
    else if (f < 12) { int g = f - 4;  qt = 4  + (g >> 1); ch = g & 1; }
    else if (f < 24) { int g = f - 12; qt = 8  + g / 3;    ch = g % 3; }
    else             { int g = f - 24; qt = 12 + (g >> 2); ch = g & 3; }
    const int j0 = ch * 8;
    const int j1 = min(j0 + 8, 2 * qt + 2);
    const int qbase = qt * 128 + wid * 32;                // wave's q origin

    // staging address precompute
    const int rK0 = tid >> 4, wK0 = tid & 15;
    const int bK0 = ((wK0 * 16) ^ ((rK0 & 7) << 4)) >> 1;
    const int rV0 = tid >> 3, wV0 = tid & 7;
    const int bV0 = ((wV0 * 16) ^ ((rV0 & 7) << 4)) >> 1;
    const u16* kbase = Kp + (size_t)(b * SS + rK0) * DD + h * HDIM + bK0;
    const u16* vbase = Vt + (size_t)(h * HDIM + rV0) * MM + b * SS + bV0;

    // Q fragments: 2 q-halves (B-frag col = q = qh*16+li)
    short8 qf[4][2];
    {
        const u16* qp0 = Q + (size_t)(b * SS + qbase + li) * DD + h * HDIM + lg * 8;
#pragma unroll
        for (int qh = 0; qh < 2; ++qh)
#pragma unroll
            for (int s = 0; s < 4; ++s)
                qf[s][qh] = *(const short8*)(qp0 + (size_t)qh * 16 * DD + s * 32);
    }

    const f32x4 zero = {0.f, 0.f, 0.f, 0.f};
    float m_r[2], l_r[2];
    m_r[0] = m_r[1] = -__builtin_inff();
    l_r[0] = l_r[1] = 0.f;
    f32x4 accO[8][2];          // O^T: row d = mb*16+lg*4+r, col q = qh*16+li
#pragma unroll
    for (int d = 0; d < 8; ++d) accO[d][0] = accO[d][1] = zero;

    for (int j = j0; j < j1; ++j) {
        // ---- stage K and V^T (single buffer) ----
#pragma unroll
        for (int i_ = 0; i_ < 4; ++i_) {
            gload_lds16(kbase + (size_t)(j * 64 + i_ * 16) * DD, &Kl[(i_ * 256 + tid) * 8]);
            gload_lds16(vbase + (size_t)(i_ * 32) * MM + j * 64, &Vl[(i_ * 256 + tid) * 8]);
        }
        __syncthreads();

        // wave-uniform: skip fully-masked diagonal tiles
        if (j * 64 <= qbase + 31) {
            // ---- scores TRANSPOSED: S^T[64 kv][32 q], A=K, B=Q ----
            f32x4 accS[4][2];
#pragma unroll
            for (int nb = 0; nb < 4; ++nb) accS[nb][0] = accS[nb][1] = zero;
            __builtin_amdgcn_s_setprio(1);
#pragma unroll
            for (int s = 0; s < 4; ++s) {
#pragma unroll
                for (int nb = 0; nb < 4; ++nb) {
                    const int R = nb * 16 + li;
                    const int e = ((s * 64 + lg * 16) ^ ((R & 7) << 4)) >> 1;
                    short8 kf = *(const short8*)(&Kl[R * 128 + e]);
#pragma unroll
                    for (int qh = 0; qh < 2; ++qh)
                        accS[nb][qh] = mfma16(kf, qf[s][qh], accS[nb][qh]);
                }
            }
            __builtin_amdgcn_s_setprio(0);

            // ---- online softmax, per-lane (2 q's), exp2 domain ----
            const bool domask = (j * 64 + 63 > qbase);
            float rmax[2];
            rmax[0] = rmax[1] = -__builtin_inff();
#pragma unroll
            for (int nb = 0; nb < 4; ++nb)
#pragma unroll
                for (int qh = 0; qh < 2; ++qh)
#pragma unroll
                    for (int r = 0; r < 4; ++r) {
                        float t = accS[nb][qh][r];
                        if (domask && (j * 64 + nb * 16 + lg * 4 + r >
                                       qbase + qh * 16 + li)) t = -__builtin_inff();
                        accS[nb][qh][r] = t;
                        rmax[qh] = fmaxf(rmax[qh], t);
                    }
#pragma unroll
            for (int qh = 0; qh < 2; ++qh) {
                rmax[qh] = fmaxf(rmax[qh], __shfl_xor(rmax[qh], 16, 64));
                rmax[qh] = fmaxf(rmax[qh], __shfl_xor(rmax[qh], 32, 64));
            }

            // defer-max (T13)
            const bool need = (rmax[0] - m_r[0] > 11.5f) || (rmax[1] - m_r[1] > 11.5f);
            if (__any(need)) {
#pragma unroll
                for (int qh = 0; qh < 2; ++qh) {
                    const float mn = fmaxf(m_r[qh], rmax[qh]);
                    const float sf = exp2f(m_r[qh] - mn);
                    m_r[qh] = mn;
                    l_r[qh] *= sf;
#pragma unroll
                    for (int mb = 0; mb < 8; ++mb)
#pragma unroll
                        for (int r = 0; r < 4; ++r) accO[mb][qh][r] *= sf;
                }
            }

            float ls[2] = {0.f, 0.f};
#pragma unroll
            for (int nb = 0; nb < 4; ++nb)
#pragma unroll
                for (int qh = 0; qh < 2; ++qh)
#pragma unroll
                    for (int r = 0; r < 4; ++r) {
                        const float e = exp2f(accS[nb][qh][r] - m_r[qh]);
                        accS[nb][qh][r] = e;
                        ls[qh] += e;
                    }
#pragma unroll
            for (int qh = 0; qh < 2; ++qh) {
                ls[qh] += __shfl_xor(ls[qh], 16, 64);
                ls[qh] += __shfl_xor(ls[qh], 32, 64);
                l_r[qh] += ls[qh];
            }

            // ---- P -> LDS, packed b64 writes ----
#pragma unroll
            for (int nb = 0; nb < 4; ++nb)
#pragma unroll
                for (int qh = 0; qh < 2; ++qh) {
                    u16x4 pk;
                    pk.x = f2bf(accS[nb][qh][0]);
                    pk.y = f2bf(accS[nb][qh][1]);
                    pk.z = f2bf(accS[nb][qh][2]);
                    pk.w = f2bf(accS[nb][qh][3]);
                    *(u16x4*)(&Pl[(wid * 32 + qh * 16 + li) * SP + nb * 16 + lg * 4]) = pk;
                }

            // ---- PV transposed: O^T += V^T @ P^T ----
            __builtin_amdgcn_s_setprio(1);
#pragma unroll
            for (int s2 = 0; s2 < 2; ++s2) {
                short8 pf[2];
#pragma unroll
                for (int qh = 0; qh < 2; ++qh)
                    pf[qh] = *(const short8*)(&Pl[(wid * 32 + qh * 16 + li) * SP +
                                                  s2 * 32 + lg * 8]);
#pragma unroll
                for (int mb = 0; mb < 8; ++mb) {
                    const int R2 = mb * 16 + li;
                    const int e2 = ((s2 * 64 + lg * 16) ^ ((R2 & 7) << 4)) >> 1;
                    short8 vf = *(const short8*)(&Vl[R2 * 64 + e2]);
#pragma unroll
                    for (int qh = 0; qh < 2; ++qh)
                        accO[mb][qh] = mfma16(vf, pf[qh], accO[mb][qh]);
                }
            }
            __builtin_amdgcn_s_setprio(0);
        }
        __syncthreads();
    }

    if (f >= 4) {
        // ---- partial epilogue: unnormalized O^T (bf16) + m,l (f32) ----
        const int pslot = (b * HH + h) * 36 + (f - 4);
        u16* po = PartO + (size_t)pslot * 16384;
#pragma unroll
        for (int mb = 0; mb < 8; ++mb)
#pragma unroll
            for (int qh = 0; qh < 2; ++qh) {
                const int q_g = wid * 32 + qh * 16 + li;
#pragma unroll
                for (int r = 0; r < 4; ++r) {
                    const int d = mb * 16 + lg * 4 + r;
                    po[d * 128 + q_g] = f2bf(accO[mb][qh][r]);
                }
            }
        if (lg == 0) {
            float* ml = PartML + (size_t)pslot * 256;
#pragma unroll
            for (int qh = 0; qh < 2; ++qh) {
                ml[wid * 32 + qh * 16 + li]       = m_r[qh];
                ml[128 + wid * 32 + qh * 16 + li] = l_r[qh];
            }
        }
    } else {
        // ---- direct epilogue: normalize, un-transpose via LDS bounce ----
        float linv[2] = {1.f / l_r[0], 1.f / l_r[1]};
        u16* Wl = lds + wid * 4096;               // 32 q x 128 d per wave
#pragma unroll
        for (int mb = 0; mb < 8; ++mb)
#pragma unroll
            for (int qh = 0; qh < 2; ++qh) {
                const int q_l = qh * 16 + li;
                const int dbase = mb * 16 + lg * 4;
                u16x4 pk;
                pk.x = f2bf(accO[mb][qh][0] * linv[qh]);
                pk.y = f2bf(accO[mb][qh][1] * linv[qh]);
                pk.z = f2bf(accO[mb][qh][2] * linv[qh]);
                pk.w = f2bf(accO[mb][qh][3] * linv[qh]);
                *(u16x4*)(&Wl[q_l * 128 + (dbase ^ ((q_l & 7) << 4))]) = pk;
            }
        const int q_l = lane >> 1;
        const int d0 = (lane & 1) * 64;
        u16* op = O + (size_t)(b * SS + qt * 128 + wid * 32 + q_l) * DD + h * HDIM + d0;
#pragma unroll
        for (int c = 0; c < 8; ++c) {
            short8 vv = *(const short8*)(&Wl[q_l * 128 + ((d0 + c * 8) ^ ((q_l & 7) << 4))]);
            *(short8*)(op + c * 8) = vv;
        }
    }
}

// Combine partials for qt >= 4: O[q][d] = sum_c w_c * PartO_c[d][q] / L
__global__ __launch_bounds__(256) void attn_combine(
    const u16* __restrict__ PartO, const float* __restrict__ PartML,
    u16* __restrict__ O)
{
    const int qt = 4 + (int)blockIdx.x;
    const int h = blockIdx.y, b = blockIdx.z;
    const int nch = qt / 4 + 1;
    // first partial slot offset for this qt (within this (b,h)'s 36 slots)
    int f0m4;
    if (qt < 8)       f0m4 = (qt - 4) * 2;
    else if (qt < 12) f0m4 = 8 + (qt - 8) * 3;
    else              f0m4 = 20 + (qt - 12) * 4;
    const int pbase = (b * HH + h) * 36 + f0m4;

    const int tid = threadIdx.x;
    const int q = tid & 127;
    const int d0 = (tid >> 7) * 64;

    float mc[4], lc[4];
#pragma unroll
    for (int c = 0; c < 4; ++c) {
        if (c < nch) {
            mc[c] = PartML[(size_t)(pbase + c) * 256 + q];
            lc[c] = PartML[(size_t)(pbase + c) * 256 + 128 + q];
        } else { mc[c] = -__builtin_inff(); lc[c] = 0.f; }
    }
    float M = fmaxf(fmaxf(mc[0], mc[1]), fmaxf(mc[2], mc[3]));
    float wc[4], L = 0.f;
#pragma unroll
    for (int c = 0; c < 4; ++c) { wc[c] = exp2f(mc[c] - M); L += wc[c] * lc[c]; }
    const float Linv = 1.f / L;

    float acc[64];
#pragma unroll
    for (int i = 0; i < 64; ++i) acc[i] = 0.f;
#pragma unroll
    for (int c = 0; c < 4; ++c) {
        if (c < nch) {
            const float w = wc[c] * Linv;
            const u16* po = PartO + (size_t)(pbase + c) * 16384 + q;
#pragma unroll
            for (int i = 0; i < 64; ++i)
                acc[i] += w * bf2f(po[(size_t)(d0 + i) * 128]);
        }
    }

    u16* op = O + (size_t)(b * SS + qt * 128 + q) * DD + h * HDIM + d0;
#pragma unroll
    for (int j = 0; j < 8; ++j) {
        short8 vv;
#pragma unroll
        for (int e = 0; e < 8; ++e) vv[e] = (short)f2bf(acc[j * 8 + e]);
        *(short8*)(op + j * 8) = vv;
    }
}

extern "C" void kernel_launch(void* const* d_in, const int* in_sizes, int n_in,
                              void* d_out, int out_size, void* d_ws, size_t ws_size,
                              hipStream_t stream)
{
    const float* queries = (const float*)d_in[0];
    const float* keys    = (const float*)d_in[1];
    const float* values  = (const float*)d_in[2];
    // d_in[3] = attention_mask: causal by construction
    const float* wq = (const float*)d_in[4];
    const float* bq = (const float*)d_in[5];
    const float* wk = (const float*)d_in[6];
    const float* bk = (const float*)d_in[7];
    const float* wv = (const float*)d_in[8];
    const float* bv = (const float*)d_in[9];
    const float* wo = (const float*)d_in[10];
    const float* bo = (const float*)d_in[11];

    const int NMD = MM * DD;
    const int NWW = DD * DD;

    u16* qb  = (u16*)d_ws;                      // converted inputs (bf16), contiguous
    u16* wqb = qb  + (size_t)3 * NMD;           // converted weights (wq pre-scaled)
    u16* wob = wqb + (size_t)3 * NWW;
    u16* qw  = wob + (size_t)NWW;               // q proj [M][D] (KSCALE folded)
                                                // kw = qw + NMD   [M][D]
                                                // vtw = qw + 2*NMD TRANSPOSED [D][M]
    u16* aw  = qw  + (size_t)3 * NMD;           // attention output [M][D]
    // Partials alias buffers that are DEAD after gemm_qkv:
    u16*   partO  = qb;                         // 1152 * 16384 u16 = 37.7 MB (< 50.3)
    float* partML = (float*)wqb;                // 1152 * 256 f32 = 1.18 MB (< 25.2)
    (void)in_sizes; (void)n_in; (void)out_size; (void)ws_size;

    dim3 blk(256);
    dim3 gridC(2048);
    dim3 gridQKV(MM / 128, DD / 128, 3);        // (32, 16, 3) = 1536 blocks
    dim3 gridO(MM / 128, DD / 128);             // (32, 16)
    dim3 gridA(40, HH, BB);                     // (40, 16, 2) = 1280 blocks
    dim3 gridX(12, HH, BB);                     // combine: qt 4..15

    conv_all<<<gridC, blk, 0, stream>>>(queries, keys, values, wq, wk, wv, wo, qb);
    gemm_qkv<<<gridQKV, blk, 0, stream>>>(qb, wqb, bq, bk, bv, qw);
    flash_attn<<<gridA, blk, 0, stream>>>(qw, qw + (size_t)NMD, qw + (size_t)2 * NMD, aw,
                                          partO, partML);
    attn_combine<<<gridX, blk, 0, stream>>>(partO, partML, aw);
    gemm_out<<<gridO, blk, 0, stream>>>(aw, wob, bo, (float*)d_out);
}